// Round 12
// baseline (377.739 us; speedup 1.0000x reference)
//
#include <hip/hip_runtime.h>

typedef unsigned short u16;
typedef short bf16x8 __attribute__((ext_vector_type(8)));
typedef float f32x4 __attribute__((ext_vector_type(4)));

#define GLB __attribute__((address_space(1)))
#define LDSAS __attribute__((address_space(3)))

constexpr int S = 2048, D = 4096, NH = 32, NHK = 8, DHD = 128;
constexpr int NQKV = 6144;  // 4096 q + 1024 k + 1024 v

__device__ __forceinline__ u16 f2b(float f) {
    union { float f; unsigned u; } v; v.f = f;
    return (u16)((v.u + 0x7fffu + ((v.u >> 16) & 1u)) >> 16);
}
__device__ __forceinline__ float b2f(u16 b) {
    union { unsigned u; float f; } v; v.u = ((unsigned)b) << 16;
    return v.f;
}
__device__ __forceinline__ void gload16(const void* g, void* l) {
    __builtin_amdgcn_global_load_lds((const GLB unsigned int*)g,
                                     (LDSAS unsigned int*)l, 16, 0, 0);
}
#if __has_builtin(__builtin_amdgcn_exp2f)
__device__ __forceinline__ float exp2fast(float x) { return __builtin_amdgcn_exp2f(x); }
#else
__device__ __forceinline__ float exp2fast(float x) { return __expf(0.6931471805599453f * x); }
#endif

// Accurate sin/cos for large args: reduce to revolutions in [0,1), then v_sin/v_cos.
__device__ __forceinline__ void sincos_big(float ang, float* sn, float* cs) {
#if __has_builtin(__builtin_amdgcn_sinf) && __has_builtin(__builtin_amdgcn_cosf)
    float rev = ang * 0.15915494309189535f;  // 1/(2*pi)
    rev = rev - floorf(rev);                 // [0,1)
    *sn = __builtin_amdgcn_sinf(rev);
    *cs = __builtin_amdgcn_cosf(rev);
#else
    *sn = sinf(ang);
    *cs = cosf(ang);
#endif
}

// ---------------- f32 -> bf16 elementwise (8/thread) ----------------
__global__ __launch_bounds__(256) void cvt_x(const float* __restrict__ in,
                                             u16* __restrict__ out, int n8) {
    int i = blockIdx.x * 256 + threadIdx.x;
    if (i >= n8) return;
    const float4* p = (const float4*)in + (size_t)i * 2;
    float4 a = p[0], b = p[1];
    uint4 o;
    o.x = f2b(a.x) | ((unsigned)f2b(a.y) << 16);
    o.y = f2b(a.z) | ((unsigned)f2b(a.w) << 16);
    o.z = f2b(b.x) | ((unsigned)f2b(b.y) << 16);
    o.w = f2b(b.z) | ((unsigned)f2b(b.w) << 16);
    *(uint4*)(out + (size_t)i * 8) = o;
}

// ---------------- sum of two bf16 partials -> f32 (8/thread) ----------------
__global__ __launch_bounds__(256) void red2(const u16* __restrict__ P,
                                            float* __restrict__ out, int n8) {
    int i = blockIdx.x * 256 + threadIdx.x;
    if (i >= n8) return;
    uint4 a = *(const uint4*)(P + (size_t)i * 8);
    uint4 b = *(const uint4*)(P + (size_t)(8388608) + (size_t)i * 8);
    float4 o0, o1;
    o0.x = b2f((u16)a.x) + b2f((u16)b.x);
    o0.y = b2f((u16)(a.x >> 16)) + b2f((u16)(b.x >> 16));
    o0.z = b2f((u16)a.y) + b2f((u16)b.y);
    o0.w = b2f((u16)(a.y >> 16)) + b2f((u16)(b.y >> 16));
    o1.x = b2f((u16)a.z) + b2f((u16)b.z);
    o1.y = b2f((u16)(a.z >> 16)) + b2f((u16)(b.z >> 16));
    o1.z = b2f((u16)a.w) + b2f((u16)b.w);
    o1.w = b2f((u16)(a.w >> 16)) + b2f((u16)(b.w >> 16));
    float4* q = (float4*)(out + (size_t)i * 8);
    q[0] = o0; q[1] = o1;
}

// ---------------- f32 [R][C] -> bf16 [C][R] ----------------
__global__ __launch_bounds__(256) void tconv(const float* __restrict__ in,
                                             u16* __restrict__ out, int R, int C) {
    __shared__ float t[64][65];
    int r0 = blockIdx.y * 64, c0 = blockIdx.x * 64;
    int tx = threadIdx.x & 63, ty = threadIdx.x >> 6;
#pragma unroll
    for (int i = 0; i < 64; i += 4)
        t[ty + i][tx] = in[(size_t)(r0 + ty + i) * C + c0 + tx];
    __syncthreads();
#pragma unroll
    for (int i = 0; i < 64; i += 4)
        out[(size_t)(c0 + ty + i) * R + r0 + tx] = f2b(t[tx][ty + i]);
}

// ---------------- bf16 V (QKV cols 5120..6143) -> Vt [hk][d][s] ----------------
__global__ __launch_bounds__(256) void vtrans(const u16* __restrict__ QKV,
                                              u16* __restrict__ Vt) {
    __shared__ u16 t[64][65];
    int hk = blockIdx.z;
    int s0 = blockIdx.x * 64, d0 = blockIdx.y * 64;
    int tx = threadIdx.x & 63, ty = threadIdx.x >> 6;
#pragma unroll
    for (int i = 0; i < 64; i += 4)
        t[ty + i][tx] = QKV[(size_t)(s0 + ty + i) * NQKV + 5120 + hk * 128 + d0 + tx];
    __syncthreads();
#pragma unroll
    for (int i = 0; i < 64; i += 4)
        Vt[(size_t)hk * (128 * 2048) + (size_t)(d0 + ty + i) * 2048 + s0 + tx] = t[tx][ty + i];
}

// ---------------- RoPE in place, bf16, stride NQKV; scale folded in ----------------
template <int NHEADS>
__global__ __launch_bounds__(256) void rope2(u16* __restrict__ T,
                                             const int* __restrict__ pos, float scale) {
    int idx = blockIdx.x * 256 + threadIdx.x;
    int d = idx & 63;
    int h = (idx >> 6) & (NHEADS - 1);
    int s = idx >> (6 + (NHEADS == 32 ? 5 : 3));
    float p = (float)pos[s];
    float inv = __expf(-(float)d * 0.14391156531310576f);  // 10000^(-d/64)
    float ang = p * inv;
    float sn, cs;
    sincos_big(ang, &sn, &cs);
    size_t base = (size_t)s * NQKV + h * 128 + d;
    float x1 = b2f(T[base]), x2 = b2f(T[base + 64]);
    T[base]      = f2b((x1 * cs - x2 * sn) * scale);
    T[base + 64] = f2b((x2 * cs + x1 * sn) * scale);
}

// ---------------- GEMM S: m97-structure, BK=64, XOR swizzle, optional split-K ----------------
// 128x128 tile, 4 waves, 32 KB LDS. kch K-slices of klen each; slice ks writes
// to Cout + ks*2048*N (bf16 partials reduced by red2, or single slice direct).
template <bool BF16OUT>
__global__ __launch_bounds__(256) void gemmS(const u16* __restrict__ A,
                                             const u16* __restrict__ Bt,
                                             void* __restrict__ Cout,
                                             int N, int Kstride, int nbx,
                                             int kch, int klen) {
    __shared__ u16 Asm[128 * 64];  // 16 KB
    __shared__ u16 Bsm[128 * 64];  // 16 KB
    const int cpx = (int)gridDim.x >> 3;
    const int b = ((int)blockIdx.x & 7) * cpx + ((int)blockIdx.x >> 3);
    const int per = (int)gridDim.x / kch;
    const int ks = b / per, ib = b - ks * per;
    const int by = ib / nbx, bx = ib - by * nbx;
    const int m0 = by * 128, n0 = bx * 128;
    const int kbeg = ks * klen;
    const size_t obase = (size_t)ks * 2048 * N;
    const int tid = threadIdx.x, lane = tid & 63, wave = tid >> 6;
    const int l15 = lane & 15, l4 = lane >> 4;
    const int wm = wave >> 1, wn = wave & 1;
    f32x4 acc[4][4] = {};

    for (int k0 = kbeg; k0 < kbeg + klen; k0 += 64) {
        __syncthreads();
#pragma unroll
        for (int u = 0; u < 4; ++u) {
            int s = u * 256 + tid;
            int row = s >> 3, cs = (s & 7) ^ (row & 7);
            gload16(A  + (size_t)(m0 + row) * Kstride + k0 + cs * 8, Asm + s * 8);
            gload16(Bt + (size_t)(n0 + row) * Kstride + k0 + cs * 8, Bsm + s * 8);
        }
        __syncthreads();
        bf16x8 af[4][2], bf[4][2];
#pragma unroll
        for (int i = 0; i < 4; ++i)
#pragma unroll
            for (int kk = 0; kk < 2; ++kk) {
                int row = wm * 64 + i * 16 + l15;
                int cc = (kk * 4 + l4) ^ (row & 7);
                af[i][kk] = *(const bf16x8*)(Asm + row * 64 + cc * 8);
            }
#pragma unroll
        for (int j = 0; j < 4; ++j)
#pragma unroll
            for (int kk = 0; kk < 2; ++kk) {
                int row = wn * 64 + j * 16 + l15;
                int cc = (kk * 4 + l4) ^ (row & 7);
                bf[j][kk] = *(const bf16x8*)(Bsm + row * 64 + cc * 8);
            }
#pragma unroll
        for (int i = 0; i < 4; ++i)
#pragma unroll
            for (int j = 0; j < 4; ++j)
#pragma unroll
                for (int kk = 0; kk < 2; ++kk)
                    acc[i][j] = __builtin_amdgcn_mfma_f32_16x16x32_bf16(af[i][kk], bf[j][kk], acc[i][j], 0, 0, 0);
    }
#pragma unroll
    for (int i = 0; i < 4; ++i)
#pragma unroll
        for (int j = 0; j < 4; ++j) {
            int col  = n0 + wn * 64 + j * 16 + l15;
            int rowb = m0 + wm * 64 + i * 16 + l4 * 4;
#pragma unroll
            for (int r = 0; r < 4; ++r) {
                if (BF16OUT)
                    ((u16*)Cout)[obase + (size_t)(rowb + r) * N + col] = f2b(acc[i][j][r]);
                else
                    ((float*)Cout)[obase + (size_t)(rowb + r) * N + col] = acc[i][j][r];
            }
        }
}

// ---------------- Flash attention v4: balanced pairs + deferred softmax reductions ----------------
__global__ __launch_bounds__(256) void attn3(const u16* __restrict__ QKV,
                                             const u16* __restrict__ Vt,
                                             u16* __restrict__ O) {
    __shared__ u16 Ksm[2][64 * 128];  // [kv][d-chunk swz]
    __shared__ u16 Vsm[2][128 * 64];  // [d][kv-chunk swz]
    __shared__ u16 Psm[4][16 * 64];   // per-wave P tile, swz
    const int orig = blockIdx.x;
    const int swz = (orig & 7) * 64 + (orig >> 3);   // 512 = 8*64, bijective
    const int h = swz >> 4, p = swz & 15;
    const int hk = h >> 2;
    const int tid = threadIdx.x, wave = tid >> 6, lane = tid & 63;
    const int l15 = lane & 15, l4 = lane >> 4;
    const u16* Qp = QKV + h * 128;
    const u16* Kp = QKV + 4096 + hk * 128;
    const u16* Vp = Vt + (size_t)hk * (128 * 2048);

    auto stage = [&](int kb, int b) {
#pragma unroll
        for (int it = 0; it < 4; ++it) {
            int L = it * 256 + tid;
            int krow = L >> 4, kslot = L & 15;
            int kcs = (kslot & 8) | ((kslot ^ krow) & 7);
            gload16(Kp + (size_t)(kb * 64 + krow) * NQKV + kcs * 8, &Ksm[b][L * 8]);
            int vrow = L >> 3, vslot = L & 7;
            int vcs = (vslot ^ vrow) & 7;
            gload16(Vp + (size_t)vrow * 2048 + kb * 64 + vcs * 8, &Vsm[b][L * 8]);
        }
    };

#pragma unroll 1
    for (int pass = 0; pass < 2; ++pass) {
        const int qt = pass ? p : 31 - p;
        const int qr0 = qt * 64 + wave * 16;
        const int nkb = qt + 1;

        bf16x8 qf[4];
        {
            const u16* qrow = Qp + (size_t)(qr0 + l15) * NQKV;
#pragma unroll
            for (int c = 0; c < 4; ++c)
                qf[c] = *(const bf16x8*)(qrow + c * 32 + l4 * 8);
        }
        float mrow[4], lsum[4];  // lsum = per-lane partial row sum
#pragma unroll
        for (int r = 0; r < 4; ++r) { mrow[r] = -1e30f; lsum[r] = 0.f; }
        f32x4 o[8] = {};

        stage(0, 0);
#pragma unroll 1
        for (int kb = 0; kb < nkb; ++kb) {
            const int cur = kb & 1;
            if (kb + 1 < nkb) {
                stage(kb + 1, cur ^ 1);
                asm volatile("s_waitcnt vmcnt(8)" ::: "memory");
            } else {
                asm volatile("s_waitcnt vmcnt(0)" ::: "memory");
            }
            __builtin_amdgcn_s_barrier();

            if (kb * 64 <= qr0 + 15) {  // wave has unmasked work
                const u16* Kb_ = Ksm[cur];
                const u16* Vb_ = Vsm[cur];
                const bool diag = (kb * 64 + 63 > qr0);
                // ---- S = Q K^T (log2 domain) ----
                f32x4 sc[4] = {};
#pragma unroll
                for (int f = 0; f < 4; ++f) {
                    const int kv = f * 16 + l15;
#pragma unroll
                    for (int c = 0; c < 4; ++c) {
                        int cd = c * 4 + l4;
                        int cpos = (cd & 8) | ((cd ^ kv) & 7);
                        bf16x8 kf = *(const bf16x8*)(Kb_ + kv * 128 + cpos * 8);
                        sc[f] = __builtin_amdgcn_mfma_f32_16x16x32_bf16(qf[c], kf, sc[f], 0, 0, 0);
                    }
                }
                if (diag) {
#pragma unroll
                    for (int f = 0; f < 4; ++f) {
                        int col = kb * 64 + f * 16 + l15;
#pragma unroll
                        for (int r = 0; r < 4; ++r) {
                            int row = qr0 + l4 * 4 + r;
                            if (col > row) sc[f][r] = -1e30f;
                        }
                    }
                }
                // lane-local max + defer trigger (P <= 2^8 preserved via __any)
                float bm[4];
#pragma unroll
                for (int r = 0; r < 4; ++r)
                    bm[r] = fmaxf(fmaxf(sc[0][r], sc[1][r]), fmaxf(sc[2][r], sc[3][r]));
                bool need = false;
#pragma unroll
                for (int r = 0; r < 4; ++r) need = need || (bm[r] > mrow[r] + 8.0f);
                if (__any((int)need)) {
#pragma unroll
                    for (int msk = 1; msk < 16; msk <<= 1)
#pragma unroll
                        for (int r = 0; r < 4; ++r) bm[r] = fmaxf(bm[r], __shfl_xor(bm[r], msk));
                    float al[4];
#pragma unroll
                    for (int r = 0; r < 4; ++r) {
                        float mn = fmaxf(mrow[r], bm[r]);
                        al[r] = exp2fast(mrow[r] - mn);
                        mrow[r] = mn;
                        lsum[r] *= al[r];  // per-lane partial scales uniformly
                    }
#pragma unroll
                    for (int n = 0; n < 8; ++n)
#pragma unroll
                        for (int r = 0; r < 4; ++r) o[n][r] *= al[r];
                }
                // P = exp2(S - m): accumulate per-lane partial sums only
#pragma unroll
                for (int f = 0; f < 4; ++f) {
#pragma unroll
                    for (int r = 0; r < 4; ++r) {
                        float pw = exp2fast(sc[f][r] - mrow[r]);
                        lsum[r] += pw;
                        int q = l4 * 4 + r;
                        int kvc = f * 2 + (l15 >> 3);
                        int slot = (kvc ^ q) & 7;
                        Psm[wave][q * 64 + slot * 8 + (l15 & 7)] = f2b(pw);
                    }
                }

                asm volatile("s_waitcnt lgkmcnt(0)" ::: "memory");
                bf16x8 pf[2];
#pragma unroll
                for (int c = 0; c < 2; ++c) {
                    int chc = c * 4 + l4;
                    int slot = (chc ^ l15) & 7;
                    pf[c] = *(const bf16x8*)(&Psm[wave][l15 * 64 + slot * 8]);
                }
#pragma unroll
                for (int n = 0; n < 8; ++n) {
                    int d = n * 16 + l15;
                    bf16x8 vf[2];
#pragma unroll
                    for (int c = 0; c < 2; ++c) {
                        int ch = c * 4 + l4;
                        int slot = (ch ^ d) & 7;
                        vf[c] = *(const bf16x8*)(Vb_ + d * 64 + slot * 8);
                    }
#pragma unroll
                    for (int c = 0; c < 2; ++c)
                        o[n] = __builtin_amdgcn_mfma_f32_16x16x32_bf16(pf[c], vf[c], o[n], 0, 0, 0);
                }
            }  // active
            asm volatile("s_waitcnt lgkmcnt(0)" ::: "memory");
            __builtin_amdgcn_s_barrier();
        }

        // epilogue: reduce per-lane lsum partials across the 16-lane group, then O = acc / l
#pragma unroll
        for (int msk = 1; msk < 16; msk <<= 1)
#pragma unroll
            for (int r = 0; r < 4; ++r) lsum[r] += __shfl_xor(lsum[r], msk);
        float inv[4];
#pragma unroll
        for (int r = 0; r < 4; ++r) inv[r] = 1.0f / lsum[r];
#pragma unroll
        for (int n = 0; n < 8; ++n)
#pragma unroll
            for (int r = 0; r < 4; ++r) {
                int row = qr0 + l4 * 4 + r;
                O[(size_t)row * 4096 + h * 128 + n * 16 + l15] = f2b(o[n][r] * inv[r]);
            }
    }  // pass
}

// ---------------- launch ----------------
extern "C" void kernel_launch(void* const* d_in, const int* in_sizes, int n_in,
                              void* d_out, int out_size, void* d_ws, size_t ws_size,
                              hipStream_t stream) {
    const int*   pos = (const int*)d_in[0];
    const float* X   = (const float*)d_in[1];
    const float* Wq  = (const float*)d_in[2];
    const float* Wk  = (const float*)d_in[3];
    const float* Wv  = (const float*)d_in[4];
    const float* Wo  = (const float*)d_in[5];
    float* out = (float*)d_out;

    char* w = (char*)d_ws;
    u16* Xb    = (u16*)(w + 0);          //  16.78 MB (reused as split-K partials later)
    u16* Wqkvt = (u16*)(w + 16777216);   //  50.33 MB [6144][4096]
    u16* Wot   = (u16*)(w + 67108864);   //  33.55 MB
    u16* QKV   = (u16*)(w + 100663296);  //  25.17 MB [2048][6144]
    u16* Vtb   = (u16*)(w + 125829120);  //   4.19 MB [8][128][2048]
    u16* Ob    = (u16*)(w + 130023424);  //  16.78 MB
    u16* Pp    = (u16*)(w + 0);          //  2 x 16.78 MB partials (Xb+Wqkvt head, dead by then)

    const float SC2 = 0.08838834764831845f * 1.4426950408889634f;  // 1/sqrt(128) * log2(e)

    // conversions / weight transposes (QKV weights packed into one [6144][4096])
    cvt_x<<<4096, 256, 0, stream>>>(X, Xb, S * D / 8);
    tconv<<<dim3(64, 64), 256, 0, stream>>>(Wq, Wqkvt, 4096, 4096);
    tconv<<<dim3(16, 64), 256, 0, stream>>>(Wk, Wqkvt + (size_t)4096 * 4096, 4096, 1024);
    tconv<<<dim3(16, 64), 256, 0, stream>>>(Wv, Wqkvt + (size_t)5120 * 4096, 4096, 1024);
    tconv<<<dim3(64, 64), 256, 0, stream>>>(Wo, Wot, 4096, 4096);

    // fused QKV projection: [2048][6144] — 16 x 48 = 768 blocks (3/CU)
    gemmS<true><<<768, 256, 0, stream>>>(Xb, Wqkvt, QKV, NQKV, 4096, 48, 1, 4096);

    // rope (scale*log2e folded into Q)
    rope2<32><<<16384, 256, 0, stream>>>(QKV, pos, SC2);
    rope2<8><<<4096, 256, 0, stream>>>(QKV + 4096, pos, 1.0f);

    // V transpose
    vtrans<<<dim3(32, 2, 8), 256, 0, stream>>>(QKV, Vtb);

    // attention (balanced pairs, deferred softmax)
    attn3<<<512, 256, 0, stream>>>(QKV, Vtb, Ob);

    // output projection, split-K=2: 1024 blocks (4/CU), bf16 partials -> reduce to f32
    gemmS<true><<<1024, 256, 0, stream>>>(Ob, Wot, Pp, 4096, 4096, 32, 2, 2048);
    red2<<<4096, 256, 0, stream>>>(Pp, out, 1048576);
}

// Round 13
// 347.874 us; speedup vs baseline: 1.0859x; 1.0859x over previous
//
#include <hip/hip_runtime.h>

typedef unsigned short u16;
typedef short bf16x8 __attribute__((ext_vector_type(8)));
typedef float f32x4 __attribute__((ext_vector_type(4)));

#define GLB __attribute__((address_space(1)))
#define LDSAS __attribute__((address_space(3)))

constexpr int S = 2048, D = 4096, NH = 32, NHK = 8, DHD = 128;
constexpr int NQKV = 6144;  // 4096 q + 1024 k + 1024 v

__device__ __forceinline__ u16 f2b(float f) {
    union { float f; unsigned u; } v; v.f = f;
    return (u16)((v.u + 0x7fffu + ((v.u >> 16) & 1u)) >> 16);
}
__device__ __forceinline__ float b2f(u16 b) {
    union { unsigned u; float f; } v; v.u = ((unsigned)b) << 16;
    return v.f;
}
__device__ __forceinline__ void gload16(const void* g, void* l) {
    __builtin_amdgcn_global_load_lds((const GLB unsigned int*)g,
                                     (LDSAS unsigned int*)l, 16, 0, 0);
}
#if __has_builtin(__builtin_amdgcn_exp2f)
__device__ __forceinline__ float exp2fast(float x) { return __builtin_amdgcn_exp2f(x); }
#else
__device__ __forceinline__ float exp2fast(float x) { return __expf(0.6931471805599453f * x); }
#endif

// Accurate sin/cos for large args: reduce to revolutions in [0,1), then v_sin/v_cos.
__device__ __forceinline__ void sincos_big(float ang, float* sn, float* cs) {
#if __has_builtin(__builtin_amdgcn_sinf) && __has_builtin(__builtin_amdgcn_cosf)
    float rev = ang * 0.15915494309189535f;  // 1/(2*pi)
    rev = rev - floorf(rev);                 // [0,1)
    *sn = __builtin_amdgcn_sinf(rev);
    *cs = __builtin_amdgcn_cosf(rev);
#else
    *sn = sinf(ang);
    *cs = cosf(ang);
#endif
}

// ---------------- f32 -> bf16 elementwise (8/thread) ----------------
__global__ __launch_bounds__(256) void cvt_x(const float* __restrict__ in,
                                             u16* __restrict__ out, int n8) {
    int i = blockIdx.x * 256 + threadIdx.x;
    if (i >= n8) return;
    const float4* p = (const float4*)in + (size_t)i * 2;
    float4 a = p[0], b = p[1];
    uint4 o;
    o.x = f2b(a.x) | ((unsigned)f2b(a.y) << 16);
    o.y = f2b(a.z) | ((unsigned)f2b(a.w) << 16);
    o.z = f2b(b.x) | ((unsigned)f2b(b.y) << 16);
    o.w = f2b(b.z) | ((unsigned)f2b(b.w) << 16);
    *(uint4*)(out + (size_t)i * 8) = o;
}

// ---------------- f32 [R][C] -> bf16 [C][R] ----------------
__global__ __launch_bounds__(256) void tconv(const float* __restrict__ in,
                                             u16* __restrict__ out, int R, int C) {
    __shared__ float t[64][65];
    int r0 = blockIdx.y * 64, c0 = blockIdx.x * 64;
    int tx = threadIdx.x & 63, ty = threadIdx.x >> 6;
#pragma unroll
    for (int i = 0; i < 64; i += 4)
        t[ty + i][tx] = in[(size_t)(r0 + ty + i) * C + c0 + tx];
    __syncthreads();
#pragma unroll
    for (int i = 0; i < 64; i += 4)
        out[(size_t)(c0 + ty + i) * R + r0 + tx] = f2b(t[tx][ty + i]);
}

// ---------------- bf16 V (QKV cols 5120..6143) -> Vt [hk][d][s] ----------------
__global__ __launch_bounds__(256) void vtrans(const u16* __restrict__ QKV,
                                              u16* __restrict__ Vt) {
    __shared__ u16 t[64][65];
    int hk = blockIdx.z;
    int s0 = blockIdx.x * 64, d0 = blockIdx.y * 64;
    int tx = threadIdx.x & 63, ty = threadIdx.x >> 6;
#pragma unroll
    for (int i = 0; i < 64; i += 4)
        t[ty + i][tx] = QKV[(size_t)(s0 + ty + i) * NQKV + 5120 + hk * 128 + d0 + tx];
    __syncthreads();
#pragma unroll
    for (int i = 0; i < 64; i += 4)
        Vt[(size_t)hk * (128 * 2048) + (size_t)(d0 + ty + i) * 2048 + s0 + tx] = t[tx][ty + i];
}

// ---------------- RoPE in place, bf16, stride NQKV; scale folded in ----------------
template <int NHEADS>
__global__ __launch_bounds__(256) void rope2(u16* __restrict__ T,
                                             const int* __restrict__ pos, float scale) {
    int idx = blockIdx.x * 256 + threadIdx.x;
    int d = idx & 63;
    int h = (idx >> 6) & (NHEADS - 1);
    int s = idx >> (6 + (NHEADS == 32 ? 5 : 3));
    float p = (float)pos[s];
    float inv = __expf(-(float)d * 0.14391156531310576f);  // 10000^(-d/64)
    float ang = p * inv;
    float sn, cs;
    sincos_big(ang, &sn, &cs);
    size_t base = (size_t)s * NQKV + h * 128 + d;
    float x1 = b2f(T[base]), x2 = b2f(T[base + 64]);
    T[base]      = f2b((x1 * cs - x2 * sn) * scale);
    T[base + 64] = f2b((x2 * cs + x1 * sn) * scale);
}

// ---------------- GEMM S: m97-structure, BK=64, XOR swizzle, 2D-XCD-rect mapping ----------------
// 128x128 tile, 4 waves, 32 KB LDS. Grid = nby x nbx tiles; each XCD (blockIdx&7,
// HW round-robin) owns an (nby/2 x nbx/4) rectangle so its resident blocks share
// A-row and B-col panels in its private 4MB L2 (K streamed in near-lockstep).
template <bool BF16OUT>
__global__ __launch_bounds__(256) void gemmS(const u16* __restrict__ A,
                                             const u16* __restrict__ Bt,
                                             void* __restrict__ Cout,
                                             int N, int K, int nbx) {
    __shared__ u16 Asm[128 * 64];  // 16 KB
    __shared__ u16 Bsm[128 * 64];  // 16 KB
    const int xcd = (int)blockIdx.x & 7;
    const int slot = (int)blockIdx.x >> 3;
    const int nby = (int)gridDim.x / nbx;
    const int rpb = nby >> 1;          // rows per band (2 row-bands)
    const int cpb = nbx >> 2;          // cols per band (4 col-bands)
    const int by = (xcd >> 2) * rpb + slot / cpb;
    const int bx = (xcd & 3) * cpb + slot % cpb;
    const int m0 = by * 128, n0 = bx * 128;
    const int tid = threadIdx.x, lane = tid & 63, wave = tid >> 6;
    const int l15 = lane & 15, l4 = lane >> 4;
    const int wm = wave >> 1, wn = wave & 1;
    f32x4 acc[4][4] = {};

    for (int k0 = 0; k0 < K; k0 += 64) {
        __syncthreads();
#pragma unroll
        for (int u = 0; u < 4; ++u) {
            int s = u * 256 + tid;
            int row = s >> 3, cs = (s & 7) ^ (row & 7);
            gload16(A  + (size_t)(m0 + row) * K + k0 + cs * 8, Asm + s * 8);
            gload16(Bt + (size_t)(n0 + row) * K + k0 + cs * 8, Bsm + s * 8);
        }
        __syncthreads();
        bf16x8 af[4][2], bf[4][2];
#pragma unroll
        for (int i = 0; i < 4; ++i)
#pragma unroll
            for (int kk = 0; kk < 2; ++kk) {
                int row = wm * 64 + i * 16 + l15;
                int cc = (kk * 4 + l4) ^ (row & 7);
                af[i][kk] = *(const bf16x8*)(Asm + row * 64 + cc * 8);
            }
#pragma unroll
        for (int j = 0; j < 4; ++j)
#pragma unroll
            for (int kk = 0; kk < 2; ++kk) {
                int row = wn * 64 + j * 16 + l15;
                int cc = (kk * 4 + l4) ^ (row & 7);
                bf[j][kk] = *(const bf16x8*)(Bsm + row * 64 + cc * 8);
            }
#pragma unroll
        for (int i = 0; i < 4; ++i)
#pragma unroll
            for (int j = 0; j < 4; ++j)
#pragma unroll
                for (int kk = 0; kk < 2; ++kk)
                    acc[i][j] = __builtin_amdgcn_mfma_f32_16x16x32_bf16(af[i][kk], bf[j][kk], acc[i][j], 0, 0, 0);
    }
#pragma unroll
    for (int i = 0; i < 4; ++i)
#pragma unroll
        for (int j = 0; j < 4; ++j) {
            int col  = n0 + wn * 64 + j * 16 + l15;
            int rowb = m0 + wm * 64 + i * 16 + l4 * 4;
#pragma unroll
            for (int r = 0; r < 4; ++r) {
                if (BF16OUT)
                    ((u16*)Cout)[(size_t)(rowb + r) * N + col] = f2b(acc[i][j][r]);
                else
                    ((float*)Cout)[(size_t)(rowb + r) * N + col] = acc[i][j][r];
            }
        }
}

// ---------------- Flash attention v4: balanced pairs + deferred softmax reductions ----------------
__global__ __launch_bounds__(256) void attn3(const u16* __restrict__ QKV,
                                             const u16* __restrict__ Vt,
                                             u16* __restrict__ O) {
    __shared__ u16 Ksm[2][64 * 128];  // [kv][d-chunk swz]
    __shared__ u16 Vsm[2][128 * 64];  // [d][kv-chunk swz]
    __shared__ u16 Psm[4][16 * 64];   // per-wave P tile, swz
    const int orig = blockIdx.x;
    const int swz = (orig & 7) * 64 + (orig >> 3);   // 512 = 8*64, bijective
    const int h = swz >> 4, p = swz & 15;
    const int hk = h >> 2;
    const int tid = threadIdx.x, wave = tid >> 6, lane = tid & 63;
    const int l15 = lane & 15, l4 = lane >> 4;
    const u16* Qp = QKV + h * 128;
    const u16* Kp = QKV + 4096 + hk * 128;
    const u16* Vp = Vt + (size_t)hk * (128 * 2048);

    auto stage = [&](int kb, int b) {
#pragma unroll
        for (int it = 0; it < 4; ++it) {
            int L = it * 256 + tid;
            int krow = L >> 4, kslot = L & 15;
            int kcs = (kslot & 8) | ((kslot ^ krow) & 7);
            gload16(Kp + (size_t)(kb * 64 + krow) * NQKV + kcs * 8, &Ksm[b][L * 8]);
            int vrow = L >> 3, vslot = L & 7;
            int vcs = (vslot ^ vrow) & 7;
            gload16(Vp + (size_t)vrow * 2048 + kb * 64 + vcs * 8, &Vsm[b][L * 8]);
        }
    };

#pragma unroll 1
    for (int pass = 0; pass < 2; ++pass) {
        const int qt = pass ? p : 31 - p;
        const int qr0 = qt * 64 + wave * 16;
        const int nkb = qt + 1;

        bf16x8 qf[4];
        {
            const u16* qrow = Qp + (size_t)(qr0 + l15) * NQKV;
#pragma unroll
            for (int c = 0; c < 4; ++c)
                qf[c] = *(const bf16x8*)(qrow + c * 32 + l4 * 8);
        }
        float mrow[4], lsum[4];  // lsum = per-lane partial row sum
#pragma unroll
        for (int r = 0; r < 4; ++r) { mrow[r] = -1e30f; lsum[r] = 0.f; }
        f32x4 o[8] = {};

        stage(0, 0);
#pragma unroll 1
        for (int kb = 0; kb < nkb; ++kb) {
            const int cur = kb & 1;
            if (kb + 1 < nkb) {
                stage(kb + 1, cur ^ 1);
                asm volatile("s_waitcnt vmcnt(8)" ::: "memory");
            } else {
                asm volatile("s_waitcnt vmcnt(0)" ::: "memory");
            }
            __builtin_amdgcn_s_barrier();

            if (kb * 64 <= qr0 + 15) {  // wave has unmasked work
                const u16* Kb_ = Ksm[cur];
                const u16* Vb_ = Vsm[cur];
                const bool diag = (kb * 64 + 63 > qr0);
                // ---- S = Q K^T (log2 domain) ----
                f32x4 sc[4] = {};
#pragma unroll
                for (int f = 0; f < 4; ++f) {
                    const int kv = f * 16 + l15;
#pragma unroll
                    for (int c = 0; c < 4; ++c) {
                        int cd = c * 4 + l4;
                        int cpos = (cd & 8) | ((cd ^ kv) & 7);
                        bf16x8 kf = *(const bf16x8*)(Kb_ + kv * 128 + cpos * 8);
                        sc[f] = __builtin_amdgcn_mfma_f32_16x16x32_bf16(qf[c], kf, sc[f], 0, 0, 0);
                    }
                }
                if (diag) {
#pragma unroll
                    for (int f = 0; f < 4; ++f) {
                        int col = kb * 64 + f * 16 + l15;
#pragma unroll
                        for (int r = 0; r < 4; ++r) {
                            int row = qr0 + l4 * 4 + r;
                            if (col > row) sc[f][r] = -1e30f;
                        }
                    }
                }
                // lane-local max + defer trigger (P <= 2^8 preserved via __any)
                float bm[4];
#pragma unroll
                for (int r = 0; r < 4; ++r)
                    bm[r] = fmaxf(fmaxf(sc[0][r], sc[1][r]), fmaxf(sc[2][r], sc[3][r]));
                bool need = false;
#pragma unroll
                for (int r = 0; r < 4; ++r) need = need || (bm[r] > mrow[r] + 8.0f);
                if (__any((int)need)) {
#pragma unroll
                    for (int msk = 1; msk < 16; msk <<= 1)
#pragma unroll
                        for (int r = 0; r < 4; ++r) bm[r] = fmaxf(bm[r], __shfl_xor(bm[r], msk));
                    float al[4];
#pragma unroll
                    for (int r = 0; r < 4; ++r) {
                        float mn = fmaxf(mrow[r], bm[r]);
                        al[r] = exp2fast(mrow[r] - mn);
                        mrow[r] = mn;
                        lsum[r] *= al[r];  // per-lane partial scales uniformly
                    }
#pragma unroll
                    for (int n = 0; n < 8; ++n)
#pragma unroll
                        for (int r = 0; r < 4; ++r) o[n][r] *= al[r];
                }
                // P = exp2(S - m): accumulate per-lane partial sums only
#pragma unroll
                for (int f = 0; f < 4; ++f) {
#pragma unroll
                    for (int r = 0; r < 4; ++r) {
                        float pw = exp2fast(sc[f][r] - mrow[r]);
                        lsum[r] += pw;
                        int q = l4 * 4 + r;
                        int kvc = f * 2 + (l15 >> 3);
                        int slot = (kvc ^ q) & 7;
                        Psm[wave][q * 64 + slot * 8 + (l15 & 7)] = f2b(pw);
                    }
                }

                asm volatile("s_waitcnt lgkmcnt(0)" ::: "memory");
                bf16x8 pf[2];
#pragma unroll
                for (int c = 0; c < 2; ++c) {
                    int chc = c * 4 + l4;
                    int slot = (chc ^ l15) & 7;
                    pf[c] = *(const bf16x8*)(&Psm[wave][l15 * 64 + slot * 8]);
                }
#pragma unroll
                for (int n = 0; n < 8; ++n) {
                    int d = n * 16 + l15;
                    bf16x8 vf[2];
#pragma unroll
                    for (int c = 0; c < 2; ++c) {
                        int ch = c * 4 + l4;
                        int slot = (ch ^ d) & 7;
                        vf[c] = *(const bf16x8*)(Vb_ + d * 64 + slot * 8);
                    }
#pragma unroll
                    for (int c = 0; c < 2; ++c)
                        o[n] = __builtin_amdgcn_mfma_f32_16x16x32_bf16(pf[c], vf[c], o[n], 0, 0, 0);
                }
            }  // active
            asm volatile("s_waitcnt lgkmcnt(0)" ::: "memory");
            __builtin_amdgcn_s_barrier();
        }

        // epilogue: reduce per-lane lsum partials across the 16-lane group, then O = acc / l
#pragma unroll
        for (int msk = 1; msk < 16; msk <<= 1)
#pragma unroll
            for (int r = 0; r < 4; ++r) lsum[r] += __shfl_xor(lsum[r], msk);
        float inv[4];
#pragma unroll
        for (int r = 0; r < 4; ++r) inv[r] = 1.0f / lsum[r];
#pragma unroll
        for (int n = 0; n < 8; ++n)
#pragma unroll
            for (int r = 0; r < 4; ++r) {
                int row = qr0 + l4 * 4 + r;
                O[(size_t)row * 4096 + h * 128 + n * 16 + l15] = f2b(o[n][r] * inv[r]);
            }
    }  // pass
}

// ---------------- launch ----------------
extern "C" void kernel_launch(void* const* d_in, const int* in_sizes, int n_in,
                              void* d_out, int out_size, void* d_ws, size_t ws_size,
                              hipStream_t stream) {
    const int*   pos = (const int*)d_in[0];
    const float* X   = (const float*)d_in[1];
    const float* Wq  = (const float*)d_in[2];
    const float* Wk  = (const float*)d_in[3];
    const float* Wv  = (const float*)d_in[4];
    const float* Wo  = (const float*)d_in[5];
    float* out = (float*)d_out;

    char* w = (char*)d_ws;
    u16* Xb    = (u16*)(w + 0);          //  16.78 MB
    u16* Wqkvt = (u16*)(w + 16777216);   //  50.33 MB [6144][4096]
    u16* Wot   = (u16*)(w + 67108864);   //  33.55 MB
    u16* QKV   = (u16*)(w + 100663296);  //  25.17 MB [2048][6144]
    u16* Vtb   = (u16*)(w + 125829120);  //   4.19 MB [8][128][2048]
    u16* Ob    = (u16*)(w + 130023424);  //  16.78 MB

    const float SC2 = 0.08838834764831845f * 1.4426950408889634f;  // 1/sqrt(128) * log2(e)

    // conversions / weight transposes (QKV weights packed into one [6144][4096])
    cvt_x<<<4096, 256, 0, stream>>>(X, Xb, S * D / 8);
    tconv<<<dim3(64, 64), 256, 0, stream>>>(Wq, Wqkvt, 4096, 4096);
    tconv<<<dim3(16, 64), 256, 0, stream>>>(Wk, Wqkvt + (size_t)4096 * 4096, 4096, 1024);
    tconv<<<dim3(16, 64), 256, 0, stream>>>(Wv, Wqkvt + (size_t)5120 * 4096, 4096, 1024);
    tconv<<<dim3(64, 64), 256, 0, stream>>>(Wo, Wot, 4096, 4096);

    // fused QKV projection: [2048][6144] — 16 x 48 = 768 blocks (3/CU), 2D XCD rects
    gemmS<true><<<768, 256, 0, stream>>>(Xb, Wqkvt, QKV, NQKV, 4096, 48);

    // rope (scale*log2e folded into Q)
    rope2<32><<<16384, 256, 0, stream>>>(QKV, pos, SC2);
    rope2<8><<<4096, 256, 0, stream>>>(QKV + 4096, pos, 1.0f);

    // V transpose
    vtrans<<<dim3(32, 2, 8), 256, 0, stream>>>(QKV, Vtb);

    // attention (balanced pairs, deferred softmax)
    attn3<<<512, 256, 0, stream>>>(QKV, Vtb, Ob);

    // output projection (f32 out) — 16 x 32 = 512 blocks (2/CU), 2D XCD rects
    gemmS<false><<<512, 256, 0, stream>>>(Ob, Wot, out, 4096, 4096, 32);
}

// Round 14
// 344.330 us; speedup vs baseline: 1.0970x; 1.0103x over previous
//
#include <hip/hip_runtime.h>

typedef unsigned short u16;
typedef short bf16x8 __attribute__((ext_vector_type(8)));
typedef float f32x4 __attribute__((ext_vector_type(4)));

#define GLB __attribute__((address_space(1)))
#define LDSAS __attribute__((address_space(3)))

constexpr int S = 2048, D = 4096, NH = 32, NHK = 8, DHD = 128;
constexpr int NQKV = 6144;  // 4096 q + 1024 k + 1024 v

__device__ __forceinline__ u16 f2b(float f) {
    union { float f; unsigned u; } v; v.f = f;
    return (u16)((v.u + 0x7fffu + ((v.u >> 16) & 1u)) >> 16);
}
__device__ __forceinline__ float b2f(u16 b) {
    union { unsigned u; float f; } v; v.u = ((unsigned)b) << 16;
    return v.f;
}
__device__ __forceinline__ void gload16(const void* g, void* l) {
    __builtin_amdgcn_global_load_lds((const GLB unsigned int*)g,
                                     (LDSAS unsigned int*)l, 16, 0, 0);
}
#if __has_builtin(__builtin_amdgcn_exp2f)
__device__ __forceinline__ float exp2fast(float x) { return __builtin_amdgcn_exp2f(x); }
#else
__device__ __forceinline__ float exp2fast(float x) { return __expf(0.6931471805599453f * x); }
#endif

// Accurate sin/cos for large args: reduce to revolutions in [0,1), then v_sin/v_cos.
__device__ __forceinline__ void sincos_big(float ang, float* sn, float* cs) {
#if __has_builtin(__builtin_amdgcn_sinf) && __has_builtin(__builtin_amdgcn_cosf)
    float rev = ang * 0.15915494309189535f;  // 1/(2*pi)
    rev = rev - floorf(rev);                 // [0,1)
    *sn = __builtin_amdgcn_sinf(rev);
    *cs = __builtin_amdgcn_cosf(rev);
#else
    *sn = sinf(ang);
    *cs = cosf(ang);
#endif
}

// ---------------- f32 -> bf16 elementwise (8/thread) ----------------
__global__ __launch_bounds__(256) void cvt_x(const float* __restrict__ in,
                                             u16* __restrict__ out, int n8) {
    int i = blockIdx.x * 256 + threadIdx.x;
    if (i >= n8) return;
    const float4* p = (const float4*)in + (size_t)i * 2;
    float4 a = p[0], b = p[1];
    uint4 o;
    o.x = f2b(a.x) | ((unsigned)f2b(a.y) << 16);
    o.y = f2b(a.z) | ((unsigned)f2b(a.w) << 16);
    o.z = f2b(b.x) | ((unsigned)f2b(b.y) << 16);
    o.w = f2b(b.z) | ((unsigned)f2b(b.w) << 16);
    *(uint4*)(out + (size_t)i * 8) = o;
}

// ---------------- f32 [R][C] -> bf16 [C][R], vectorized (float4 in, ushort4 out) ----------------
__global__ __launch_bounds__(256) void tconvV(const float* __restrict__ in,
                                              u16* __restrict__ out, int R, int C) {
    __shared__ float t[64][65];  // pad 65: transposed scalar reads are 2-way (free)
    const int r0 = blockIdx.y * 64, c0 = blockIdx.x * 64;
    const int tid = threadIdx.x;
    const int rr = tid >> 4;          // 0..15
    const int cc = (tid & 15) * 4;    // 0,4,..,60
#pragma unroll
    for (int p = 0; p < 4; ++p) {
        int r = p * 16 + rr;
        float4 v = *(const float4*)&in[(size_t)(r0 + r) * C + c0 + cc];
        t[r][cc] = v.x; t[r][cc + 1] = v.y; t[r][cc + 2] = v.z; t[r][cc + 3] = v.w;
    }
    __syncthreads();
#pragma unroll
    for (int p = 0; p < 4; ++p) {
        int c = p * 16 + rr;
        ushort4 o;
        o.x = f2b(t[cc + 0][c]); o.y = f2b(t[cc + 1][c]);
        o.z = f2b(t[cc + 2][c]); o.w = f2b(t[cc + 3][c]);
        *(ushort4*)&out[(size_t)(c0 + c) * R + r0 + cc] = o;
    }
}

// ---------------- bf16 V (QKV cols 5120..6143) -> Vt [hk][d][s], vectorized ----------------
__global__ __launch_bounds__(256) void vtransV(const u16* __restrict__ QKV,
                                               u16* __restrict__ Vt) {
    __shared__ u16 t[64][65];
    const int hk = blockIdx.z;
    const int s0 = blockIdx.x * 64, d0 = blockIdx.y * 64;
    const int tid = threadIdx.x;
    const int rr = tid >> 4;          // 0..15
    const int cc = (tid & 15) * 4;    // 0,4,..,60
#pragma unroll
    for (int p = 0; p < 4; ++p) {
        int s = p * 16 + rr;
        ushort4 v = *(const ushort4*)&QKV[(size_t)(s0 + s) * NQKV + 5120 + hk * 128 + d0 + cc];
        t[s][cc] = v.x; t[s][cc + 1] = v.y; t[s][cc + 2] = v.z; t[s][cc + 3] = v.w;
    }
    __syncthreads();
#pragma unroll
    for (int p = 0; p < 4; ++p) {
        int d = p * 16 + rr;
        ushort4 o;
        o.x = t[cc + 0][d]; o.y = t[cc + 1][d];
        o.z = t[cc + 2][d]; o.w = t[cc + 3][d];
        *(ushort4*)&Vt[(size_t)hk * (128 * 2048) + (size_t)(d0 + d) * 2048 + s0 + cc] = o;
    }
}

// ---------------- RoPE in place on Q+K heads (merged), stride NQKV ----------------
__global__ __launch_bounds__(256) void ropeM(u16* __restrict__ T,
                                             const int* __restrict__ pos, float sc2) {
    const int hh = blockIdx.y;                       // 0..39 (0-31 Q, 32-39 K)
    const int i = blockIdx.x * 256 + threadIdx.x;    // 0..131071
    const int d = i & 63;
    const int s = i >> 6;
    const float scale = hh < 32 ? sc2 : 1.0f;
    float p = (float)pos[s];
    float inv = __expf(-(float)d * 0.14391156531310576f);  // 10000^(-d/64)
    float ang = p * inv;
    float sn, cs;
    sincos_big(ang, &sn, &cs);
    size_t base = (size_t)s * NQKV + hh * 128 + d;
    float x1 = b2f(T[base]), x2 = b2f(T[base + 64]);
    T[base]      = f2b((x1 * cs - x2 * sn) * scale);
    T[base + 64] = f2b((x2 * cs + x1 * sn) * scale);
}

// ---------------- GEMM S: m97-structure, BK=64, XOR swizzle, 2D-XCD-rect mapping ----------------
// 128x128 tile, 4 waves, 32 KB LDS. Each XCD (blockIdx&7, HW round-robin) owns an
// (nby/2 x nbx/4) rectangle; its resident blocks stream K near-lockstep so each
// 64-wide K-slice of the rect's A/B panels is fetched once into the XCD L2.
// [verified r13: FETCH 316->103 MB]
template <bool BF16OUT>
__global__ __launch_bounds__(256) void gemmS(const u16* __restrict__ A,
                                             const u16* __restrict__ Bt,
                                             void* __restrict__ Cout,
                                             int N, int K, int nbx) {
    __shared__ u16 Asm[128 * 64];  // 16 KB
    __shared__ u16 Bsm[128 * 64];  // 16 KB
    const int xcd = (int)blockIdx.x & 7;
    const int slot = (int)blockIdx.x >> 3;
    const int nby = (int)gridDim.x / nbx;
    const int rpb = nby >> 1;          // rows per band (2 row-bands)
    const int cpb = nbx >> 2;          // cols per band (4 col-bands)
    const int by = (xcd >> 2) * rpb + slot / cpb;
    const int bx = (xcd & 3) * cpb + slot % cpb;
    const int m0 = by * 128, n0 = bx * 128;
    const int tid = threadIdx.x, lane = tid & 63, wave = tid >> 6;
    const int l15 = lane & 15, l4 = lane >> 4;
    const int wm = wave >> 1, wn = wave & 1;
    f32x4 acc[4][4] = {};

    for (int k0 = 0; k0 < K; k0 += 64) {
        __syncthreads();
#pragma unroll
        for (int u = 0; u < 4; ++u) {
            int s = u * 256 + tid;
            int row = s >> 3, cs = (s & 7) ^ (row & 7);
            gload16(A  + (size_t)(m0 + row) * K + k0 + cs * 8, Asm + s * 8);
            gload16(Bt + (size_t)(n0 + row) * K + k0 + cs * 8, Bsm + s * 8);
        }
        __syncthreads();
        bf16x8 af[4][2], bf[4][2];
#pragma unroll
        for (int i = 0; i < 4; ++i)
#pragma unroll
            for (int kk = 0; kk < 2; ++kk) {
                int row = wm * 64 + i * 16 + l15;
                int cc = (kk * 4 + l4) ^ (row & 7);
                af[i][kk] = *(const bf16x8*)(Asm + row * 64 + cc * 8);
            }
#pragma unroll
        for (int j = 0; j < 4; ++j)
#pragma unroll
            for (int kk = 0; kk < 2; ++kk) {
                int row = wn * 64 + j * 16 + l15;
                int cc = (kk * 4 + l4) ^ (row & 7);
                bf[j][kk] = *(const bf16x8*)(Bsm + row * 64 + cc * 8);
            }
#pragma unroll
        for (int i = 0; i < 4; ++i)
#pragma unroll
            for (int j = 0; j < 4; ++j)
#pragma unroll
                for (int kk = 0; kk < 2; ++kk)
                    acc[i][j] = __builtin_amdgcn_mfma_f32_16x16x32_bf16(af[i][kk], bf[j][kk], acc[i][j], 0, 0, 0);
    }
#pragma unroll
    for (int i = 0; i < 4; ++i)
#pragma unroll
        for (int j = 0; j < 4; ++j) {
            int col  = n0 + wn * 64 + j * 16 + l15;
            int rowb = m0 + wm * 64 + i * 16 + l4 * 4;
#pragma unroll
            for (int r = 0; r < 4; ++r) {
                if (BF16OUT)
                    ((u16*)Cout)[(size_t)(rowb + r) * N + col] = f2b(acc[i][j][r]);
                else
                    ((float*)Cout)[(size_t)(rowb + r) * N + col] = acc[i][j][r];
            }
        }
}

// ---------------- Flash attention v4: balanced pairs + deferred softmax reductions ----------------
__global__ __launch_bounds__(256) void attn3(const u16* __restrict__ QKV,
                                             const u16* __restrict__ Vt,
                                             u16* __restrict__ O) {
    __shared__ u16 Ksm[2][64 * 128];  // [kv][d-chunk swz]
    __shared__ u16 Vsm[2][128 * 64];  // [d][kv-chunk swz]
    __shared__ u16 Psm[4][16 * 64];   // per-wave P tile, swz
    const int orig = blockIdx.x;
    const int swz = (orig & 7) * 64 + (orig >> 3);   // 512 = 8*64, bijective
    const int h = swz >> 4, p = swz & 15;
    const int hk = h >> 2;
    const int tid = threadIdx.x, wave = tid >> 6, lane = tid & 63;
    const int l15 = lane & 15, l4 = lane >> 4;
    const u16* Qp = QKV + h * 128;
    const u16* Kp = QKV + 4096 + hk * 128;
    const u16* Vp = Vt + (size_t)hk * (128 * 2048);

    auto stage = [&](int kb, int b) {
#pragma unroll
        for (int it = 0; it < 4; ++it) {
            int L = it * 256 + tid;
            int krow = L >> 4, kslot = L & 15;
            int kcs = (kslot & 8) | ((kslot ^ krow) & 7);
            gload16(Kp + (size_t)(kb * 64 + krow) * NQKV + kcs * 8, &Ksm[b][L * 8]);
            int vrow = L >> 3, vslot = L & 7;
            int vcs = (vslot ^ vrow) & 7;
            gload16(Vp + (size_t)vrow * 2048 + kb * 64 + vcs * 8, &Vsm[b][L * 8]);
        }
    };

#pragma unroll 1
    for (int pass = 0; pass < 2; ++pass) {
        const int qt = pass ? p : 31 - p;
        const int qr0 = qt * 64 + wave * 16;
        const int nkb = qt + 1;

        bf16x8 qf[4];
        {
            const u16* qrow = Qp + (size_t)(qr0 + l15) * NQKV;
#pragma unroll
            for (int c = 0; c < 4; ++c)
                qf[c] = *(const bf16x8*)(qrow + c * 32 + l4 * 8);
        }
        float mrow[4], lsum[4];  // lsum = per-lane partial row sum
#pragma unroll
        for (int r = 0; r < 4; ++r) { mrow[r] = -1e30f; lsum[r] = 0.f; }
        f32x4 o[8] = {};

        stage(0, 0);
#pragma unroll 1
        for (int kb = 0; kb < nkb; ++kb) {
            const int cur = kb & 1;
            if (kb + 1 < nkb) {
                stage(kb + 1, cur ^ 1);
                asm volatile("s_waitcnt vmcnt(8)" ::: "memory");
            } else {
                asm volatile("s_waitcnt vmcnt(0)" ::: "memory");
            }
            __builtin_amdgcn_s_barrier();

            if (kb * 64 <= qr0 + 15) {  // wave has unmasked work
                const u16* Kb_ = Ksm[cur];
                const u16* Vb_ = Vsm[cur];
                const bool diag = (kb * 64 + 63 > qr0);
                // ---- S = Q K^T (log2 domain) ----
                f32x4 sc[4] = {};
#pragma unroll
                for (int f = 0; f < 4; ++f) {
                    const int kv = f * 16 + l15;
#pragma unroll
                    for (int c = 0; c < 4; ++c) {
                        int cd = c * 4 + l4;
                        int cpos = (cd & 8) | ((cd ^ kv) & 7);
                        bf16x8 kf = *(const bf16x8*)(Kb_ + kv * 128 + cpos * 8);
                        sc[f] = __builtin_amdgcn_mfma_f32_16x16x32_bf16(qf[c], kf, sc[f], 0, 0, 0);
                    }
                }
                if (diag) {
#pragma unroll
                    for (int f = 0; f < 4; ++f) {
                        int col = kb * 64 + f * 16 + l15;
#pragma unroll
                        for (int r = 0; r < 4; ++r) {
                            int row = qr0 + l4 * 4 + r;
                            if (col > row) sc[f][r] = -1e30f;
                        }
                    }
                }
                // lane-local max + defer trigger (P <= 2^8 preserved via __any)
                float bm[4];
#pragma unroll
                for (int r = 0; r < 4; ++r)
                    bm[r] = fmaxf(fmaxf(sc[0][r], sc[1][r]), fmaxf(sc[2][r], sc[3][r]));
                bool need = false;
#pragma unroll
                for (int r = 0; r < 4; ++r) need = need || (bm[r] > mrow[r] + 8.0f);
                if (__any((int)need)) {
#pragma unroll
                    for (int msk = 1; msk < 16; msk <<= 1)
#pragma unroll
                        for (int r = 0; r < 4; ++r) bm[r] = fmaxf(bm[r], __shfl_xor(bm[r], msk));
                    float al[4];
#pragma unroll
                    for (int r = 0; r < 4; ++r) {
                        float mn = fmaxf(mrow[r], bm[r]);
                        al[r] = exp2fast(mrow[r] - mn);
                        mrow[r] = mn;
                        lsum[r] *= al[r];  // per-lane partial scales uniformly
                    }
#pragma unroll
                    for (int n = 0; n < 8; ++n)
#pragma unroll
                        for (int r = 0; r < 4; ++r) o[n][r] *= al[r];
                }
                // P = exp2(S - m): accumulate per-lane partial sums only
#pragma unroll
                for (int f = 0; f < 4; ++f) {
#pragma unroll
                    for (int r = 0; r < 4; ++r) {
                        float pw = exp2fast(sc[f][r] - mrow[r]);
                        lsum[r] += pw;
                        int q = l4 * 4 + r;
                        int kvc = f * 2 + (l15 >> 3);
                        int slot = (kvc ^ q) & 7;
                        Psm[wave][q * 64 + slot * 8 + (l15 & 7)] = f2b(pw);
                    }
                }

                asm volatile("s_waitcnt lgkmcnt(0)" ::: "memory");
                bf16x8 pf[2];
#pragma unroll
                for (int c = 0; c < 2; ++c) {
                    int chc = c * 4 + l4;
                    int slot = (chc ^ l15) & 7;
                    pf[c] = *(const bf16x8*)(&Psm[wave][l15 * 64 + slot * 8]);
                }
#pragma unroll
                for (int n = 0; n < 8; ++n) {
                    int d = n * 16 + l15;
                    bf16x8 vf[2];
#pragma unroll
                    for (int c = 0; c < 2; ++c) {
                        int ch = c * 4 + l4;
                        int slot = (ch ^ d) & 7;
                        vf[c] = *(const bf16x8*)(Vb_ + d * 64 + slot * 8);
                    }
#pragma unroll
                    for (int c = 0; c < 2; ++c)
                        o[n] = __builtin_amdgcn_mfma_f32_16x16x32_bf16(pf[c], vf[c], o[n], 0, 0, 0);
                }
            }  // active
            asm volatile("s_waitcnt lgkmcnt(0)" ::: "memory");
            __builtin_amdgcn_s_barrier();
        }

        // epilogue: reduce per-lane lsum partials across the 16-lane group, then O = acc / l
#pragma unroll
        for (int msk = 1; msk < 16; msk <<= 1)
#pragma unroll
            for (int r = 0; r < 4; ++r) lsum[r] += __shfl_xor(lsum[r], msk);
        float inv[4];
#pragma unroll
        for (int r = 0; r < 4; ++r) inv[r] = 1.0f / lsum[r];
#pragma unroll
        for (int n = 0; n < 8; ++n)
#pragma unroll
            for (int r = 0; r < 4; ++r) {
                int row = qr0 + l4 * 4 + r;
                O[(size_t)row * 4096 + h * 128 + n * 16 + l15] = f2b(o[n][r] * inv[r]);
            }
    }  // pass
}

// ---------------- launch ----------------
extern "C" void kernel_launch(void* const* d_in, const int* in_sizes, int n_in,
                              void* d_out, int out_size, void* d_ws, size_t ws_size,
                              hipStream_t stream) {
    const int*   pos = (const int*)d_in[0];
    const float* X   = (const float*)d_in[1];
    const float* Wq  = (const float*)d_in[2];
    const float* Wk  = (const float*)d_in[3];
    const float* Wv  = (const float*)d_in[4];
    const float* Wo  = (const float*)d_in[5];
    float* out = (float*)d_out;

    char* w = (char*)d_ws;
    u16* Xb    = (u16*)(w + 0);          //  16.78 MB
    u16* Wqkvt = (u16*)(w + 16777216);   //  50.33 MB [6144][4096]
    u16* Wot   = (u16*)(w + 67108864);   //  33.55 MB
    u16* QKV   = (u16*)(w + 100663296);  //  25.17 MB [2048][6144]
    u16* Vtb   = (u16*)(w + 125829120);  //   4.19 MB [8][128][2048]
    u16* Ob    = (u16*)(w + 130023424);  //  16.78 MB

    const float SC2 = 0.08838834764831845f * 1.4426950408889634f;  // 1/sqrt(128) * log2(e)

    // conversions / weight transposes (QKV weights packed into one [6144][4096])
    cvt_x<<<4096, 256, 0, stream>>>(X, Xb, S * D / 8);
    tconvV<<<dim3(64, 64), 256, 0, stream>>>(Wq, Wqkvt, 4096, 4096);
    tconvV<<<dim3(16, 64), 256, 0, stream>>>(Wk, Wqkvt + (size_t)4096 * 4096, 4096, 1024);
    tconvV<<<dim3(16, 64), 256, 0, stream>>>(Wv, Wqkvt + (size_t)5120 * 4096, 4096, 1024);
    tconvV<<<dim3(64, 64), 256, 0, stream>>>(Wo, Wot, 4096, 4096);

    // fused QKV projection: [2048][6144] — 16 x 48 = 768 blocks (3/CU), 2D XCD rects
    gemmS<true><<<768, 256, 0, stream>>>(Xb, Wqkvt, QKV, NQKV, 4096, 48);

    // rope on Q+K heads, single launch (scale*log2e folded into Q)
    ropeM<<<dim3(512, 40), 256, 0, stream>>>(QKV, pos, SC2);

    // V transpose (vectorized)
    vtransV<<<dim3(32, 2, 8), 256, 0, stream>>>(QKV, Vtb);

    // attention (balanced pairs, deferred softmax)
    attn3<<<512, 256, 0, stream>>>(QKV, Vtb, Ob);

    // output projection (f32 out) — 16 x 32 = 512 blocks (2/CU), 2D XCD rects
    gemmS<false><<<512, 256, 0, stream>>>(Ob, Wot, out, 4096, 4096, 32);
}